// Round 9
// baseline (381.483 us; speedup 1.0000x reference)
//
#include <hip/hip_runtime.h>

#define Bb 16
#define Nn 200
#define NM1 199
#define Uu 64
#define EPSBN 1e-5f
#define SLOPE 0.01f
#define SPREAD 64
#define ETS 72   // f16 elems per Et row (64 + 8 pad)
#define ZSH 36   // f32 elems per zbuf row (32 + 4 pad), 2-phase transform
#define XST 66   // slab row stride (f32) in k_first/k_p1s

typedef _Float16 f16;
typedef __attribute__((ext_vector_type(8))) _Float16 f16x8;
typedef __attribute__((ext_vector_type(2))) _Float16 f16x2;
typedef __attribute__((ext_vector_type(4))) float floatx4;

// w16 tile layout: per (bn, mt) a 1024-f16 tile; chunk l (16 B) == lane l's
// A-fragment (KB0 at +0, KB1 at +512 elems). Wave-contiguous 1 KB per access.
__device__ __forceinline__ size_t tbase(int bn, int mt) {
    return ((size_t)bn * 13 + mt) * 1024;
}

// slope < 1  =>  lrelu(v) == max(v, slope*v)
__device__ __forceinline__ float lrelu(float v) { return fmaxf(v, SLOPE * v); }
__device__ __forceinline__ int dstcol(int n, int k) { return k < n ? k : k + 1; }
// v_rcp_f32 approx (~1 ulp) instead of IEEE div
__device__ __forceinline__ float sigm(float v) {
    return __builtin_amdgcn_rcpf(1.f + __expf(-v));
}

// plain (cacheable) w16 access: 85 MB fits L3
__device__ __forceinline__ f16x8 ld8(const f16* p) { return *(const f16x8*)p; }
__device__ __forceinline__ void st8(f16* p, f16x8 v) { *(f16x8*)p = v; }

// 256-thread Et staging
__device__ __forceinline__ void stageEt(const float* __restrict__ ew, f16* Et, int tid) {
    int u = tid & 63, g = tid >> 6;
#pragma unroll
    for (int pp = 0; pp < 8; ++pp) {
        int jp = g + pp * 4;
        f16x2 pk;
        pk.x = (f16)ew[(2 * jp) * Uu + u];
        pk.y = (f16)ew[(2 * jp + 1) * Uu + u];
        *(f16x2*)&Et[u * ETS + 2 * jp] = pk;
    }
}

// x-vec projections, 4 bn per block (one per wave); L0 also computes h from x
template <bool L0>
__global__ void k_xvec(const float* __restrict__ xin, const float* __restrict__ l0w,
                       const float* __restrict__ l0b, float* __restrict__ h,
                       const float* __restrict__ w1, const float* __restrict__ b1,
                       const float* __restrict__ w2, const float* __restrict__ b2,
                       const float* __restrict__ w3, const float* __restrict__ b3,
                       const float* __restrict__ w4, const float* __restrict__ b4,
                       float* __restrict__ x1, float* __restrict__ x2,
                       float* __restrict__ x3, float* __restrict__ x4,
                       float* __restrict__ spread) {
    __shared__ float hrow[4][Uu];
    int tid = threadIdx.x;
    int u = tid & 63, wv = tid >> 6;
    int bn = blockIdx.x * 4 + wv;
    if (blockIdx.x == 0) {
        for (int t = tid; t < SPREAD * 128; t += 256) spread[t] = 0.f;
    }
    float v;
    if (L0) {
        v = fmaf(xin[bn * 2], l0w[u], fmaf(xin[bn * 2 + 1], l0w[Uu + u], l0b[u]));
        v = lrelu(v);
        h[(size_t)bn * Uu + u] = v;
    } else {
        v = h[(size_t)bn * Uu + u];
    }
    hrow[wv][u] = v;  // wave-private LDS: in-order within wave, no barrier
    float a1 = b1[u], a2 = b2[u], a3 = b3[u], a4 = b4[u];
#pragma unroll 8
    for (int j = 0; j < Uu; ++j) {
        float hv = hrow[wv][j];
        a1 = fmaf(hv, w1[j * Uu + u], a1);
        a2 = fmaf(hv, w2[j * Uu + u], a2);
        a3 = fmaf(hv, w3[j * Uu + u], a3);
        a4 = fmaf(hv, w4[j * Uu + u], a4);
    }
    x1[(size_t)bn * Uu + u] = a1;
    x2[(size_t)bn * Uu + u] = a2;
    x3[(size_t)bn * Uu + u] = a3;
    x4[(size_t)bn * Uu + u] = a4;
}

// layer-0 stats + pooled; 4 bn per block (one per wave), 256 threads.
// x4[b] slab in LDS (b block-uniform: 4 | 200), Et overlaid on slab head.
// 256-thr geometry: VGPR 84 allows 12 waves/CU = 3 blocks; 3x53.2KB = 159.7KB
// fits the 160KB LDS pool. (512-thr blocks were VGPR-pinned at 8 waves/CU.)
__global__ __launch_bounds__(256, 3) void k_first(
    const float* __restrict__ adj,
    const float* __restrict__ ew1, const float* __restrict__ eb1,
    const float* __restrict__ e0w, const float* __restrict__ e0b,
    const float* __restrict__ x2a, const float* __restrict__ x3a,
    const float* __restrict__ x4a,
    float* __restrict__ pooled, float* __restrict__ spread) {
    __shared__ __align__(16) float x4L[Nn * XST];   // 52800 B; head doubles as Et
    f16* Et = (f16*)x4L;
    int tid = threadIdx.x;
    stageEt(ew1, Et, tid);
    int l = tid & 63, wv = tid >> 6;
    int r16 = l & 15, q = l >> 4;
    int bn = blockIdx.x * 4 + wv;
    int b = (blockIdx.x * 4) / Nn;
    int n = bn % Nn;
    __syncthreads();

    f16x8 B0r[4], B1r[4];
    float c2v[4];
#pragma unroll
    for (int nt = 0; nt < 4; ++nt) {
        B0r[nt] = *(const f16x8*)&Et[(nt * 16 + r16) * ETS + q * 8];
        B1r[nt] = *(const f16x8*)&Et[(nt * 16 + r16) * ETS + 32 + q * 8];
        int u = nt * 16 + r16;
        c2v[nt] = eb1[u] + x3a[(size_t)bn * Uu + u];
    }
    float e0r[2][8], e0br[2][8];
#pragma unroll
    for (int g2 = 0; g2 < 2; ++g2) {
        int ch = g2 * 32 + q * 8;
        *(float4*)&e0r[g2][0] = *(const float4*)&e0w[ch];
        *(float4*)&e0r[g2][4] = *(const float4*)&e0w[ch + 4];
        *(float4*)&e0br[g2][0] = *(const float4*)&e0b[ch];
        *(float4*)&e0br[g2][4] = *(const float4*)&e0b[ch + 4];
    }
    __syncthreads();  // all Et reads done; safe to overwrite with slab
    {
        const float* src = x4a + (size_t)b * Nn * Uu;
        for (int i = tid; i < Nn * 16; i += 256) {
            int row = i >> 4, c4 = (i & 15) << 2;
            float4 v = *(const float4*)(src + row * Uu + c4);
            float* d = &x4L[row * XST + c4];
            ((float2*)d)[0] = make_float2(v.x, v.y);
            ((float2*)d)[1] = make_float2(v.z, v.w);
        }
    }
    __syncthreads();

    const float* adjrow = adj + (size_t)bn * Nn;
    float sum[4] = {0, 0, 0, 0}, sq[4] = {0, 0, 0, 0};
    float pm[2][8];
#pragma unroll
    for (int g2 = 0; g2 < 2; ++g2)
#pragma unroll
        for (int j = 0; j < 8; ++j) pm[g2][j] = -3.402823e38f;

    float advc = adjrow[dstcol(n, r16)];
    for (int mt = 0; mt < 12; ++mt) {  // guard-free: all rows/k < NM1
        int row = mt * 16 + r16;
        int dst = dstcol(n, row);
        float advn = 0.f;
        {
            int rn = row + 16;
            if (rn < NM1) advn = adjrow[dstcol(n, rn)];
        }
        // stats gather from LDS slab
        float xs[4][4];
#pragma unroll
        for (int rr = 0; rr < 4; ++rr) {
            const float* x4r = x4L + dstcol(n, mt * 16 + q * 4 + rr) * XST;
#pragma unroll
            for (int nt = 0; nt < 4; ++nt) xs[rr][nt] = x4r[nt * 16 + r16];
        }
        float xv[2][8];
        const float* x2r = x2a + (size_t)(b * Nn + dst) * Uu;
        *(float4*)&xv[0][0] = *(const float4*)(x2r + q * 8);
        *(float4*)&xv[0][4] = *(const float4*)(x2r + q * 8 + 4);
        *(float4*)&xv[1][0] = *(const float4*)(x2r + 32 + q * 8);
        *(float4*)&xv[1][4] = *(const float4*)(x2r + 32 + q * 8 + 4);

        float adv = advc;
        float w0[2][8];
        f16x8 A0, A1;
#pragma unroll
        for (int j = 0; j < 8; ++j) {
            w0[0][j] = lrelu(fmaf(adv, e0r[0][j], e0br[0][j]));
            w0[1][j] = lrelu(fmaf(adv, e0r[1][j], e0br[1][j]));
            A0[j] = (f16)w0[0][j];
            A1[j] = (f16)w0[1][j];
        }
        floatx4 acc[4];
#pragma unroll
        for (int nt = 0; nt < 4; ++nt) {
            acc[nt] = (floatx4){0, 0, 0, 0};
            acc[nt] = __builtin_amdgcn_mfma_f32_16x16x32_f16(A0, B0r[nt], acc[nt], 0, 0, 0);
            acc[nt] = __builtin_amdgcn_mfma_f32_16x16x32_f16(A1, B1r[nt], acc[nt], 0, 0, 0);
        }
#pragma unroll
        for (int rr = 0; rr < 4; ++rr)
#pragma unroll
            for (int nt = 0; nt < 4; ++nt) {
                float z = acc[nt][rr] + c2v[nt] + xs[rr][nt];
                sum[nt] += z;
                sq[nt] = fmaf(z, z, sq[nt]);
            }
#pragma unroll
        for (int g2 = 0; g2 < 2; ++g2)
#pragma unroll
            for (int j = 0; j < 8; ++j)
                pm[g2][j] = fmaxf(pm[g2][j], sigm(w0[g2][j]) * xv[g2][j]);
        advc = advn;
    }
    {  // mt = 12 tail, guarded
        const int mt = 12;
        int row = mt * 16 + r16;
        bool rv = row < NM1;
        int dst = dstcol(n, rv ? row : 0);
        float adv = advc;
        float w0[2][8];
        f16x8 A0, A1;
#pragma unroll
        for (int j = 0; j < 8; ++j) {
            w0[0][j] = lrelu(fmaf(adv, e0r[0][j], e0br[0][j]));
            w0[1][j] = lrelu(fmaf(adv, e0r[1][j], e0br[1][j]));
            A0[j] = (f16)w0[0][j];
            A1[j] = (f16)w0[1][j];
        }
        floatx4 acc[4];
#pragma unroll
        for (int nt = 0; nt < 4; ++nt) {
            acc[nt] = (floatx4){0, 0, 0, 0};
            acc[nt] = __builtin_amdgcn_mfma_f32_16x16x32_f16(A0, B0r[nt], acc[nt], 0, 0, 0);
            acc[nt] = __builtin_amdgcn_mfma_f32_16x16x32_f16(A1, B1r[nt], acc[nt], 0, 0, 0);
        }
#pragma unroll
        for (int rr = 0; rr < 4; ++rr) {
            int k = mt * 16 + q * 4 + rr;
            if (k < NM1) {
                const float* x4r = x4L + dstcol(n, k) * XST;
#pragma unroll
                for (int nt = 0; nt < 4; ++nt) {
                    float z = acc[nt][rr] + c2v[nt] + x4r[nt * 16 + r16];
                    sum[nt] += z;
                    sq[nt] = fmaf(z, z, sq[nt]);
                }
            }
        }
        if (rv) {
            const float* x2r = x2a + (size_t)(b * Nn + dst) * Uu;
#pragma unroll
            for (int g2 = 0; g2 < 2; ++g2) {
                float xv[8];
                *(float4*)&xv[0] = *(const float4*)(x2r + g2 * 32 + q * 8);
                *(float4*)&xv[4] = *(const float4*)(x2r + g2 * 32 + q * 8 + 4);
#pragma unroll
                for (int j = 0; j < 8; ++j)
                    pm[g2][j] = fmaxf(pm[g2][j], sigm(w0[g2][j]) * xv[j]);
            }
        }
    }
#pragma unroll
    for (int nt = 0; nt < 4; ++nt) {
        sum[nt] += __shfl_xor(sum[nt], 16, 64);
        sum[nt] += __shfl_xor(sum[nt], 32, 64);
        sq[nt] += __shfl_xor(sq[nt], 16, 64);
        sq[nt] += __shfl_xor(sq[nt], 32, 64);
    }
    float* sp = spread + (size_t)(bn & (SPREAD - 1)) * 128;
    if (l < 16) {
#pragma unroll
        for (int nt = 0; nt < 4; ++nt) {
            atomicAdd(&sp[nt * 16 + l], sum[nt]);
            atomicAdd(&sp[64 + nt * 16 + l], sq[nt]);
        }
    }
#pragma unroll
    for (int g2 = 0; g2 < 2; ++g2)
#pragma unroll
        for (int j = 0; j < 8; ++j) {
            float v = pm[g2][j];
            v = fmaxf(v, __shfl_xor(v, 1, 64));
            v = fmaxf(v, __shfl_xor(v, 2, 64));
            v = fmaxf(v, __shfl_xor(v, 4, 64));
            v = fmaxf(v, __shfl_xor(v, 8, 64));
            pm[g2][j] = v;
        }
    if (r16 == 0) {
#pragma unroll
        for (int g2 = 0; g2 < 2; ++g2)
#pragma unroll
            for (int j = 0; j < 8; ++j)
                pooled[(size_t)bn * Uu + g2 * 32 + q * 8 + j] = pm[g2][j];
    }
}

// apply BN(i)+residual -> wnew (tile store). Wave-per-bn; x4 loads hoisted
// above MFMA in the guard-free main loop; mt=12 peeled. (R7 form.)
template <bool FIRST>
__global__ __launch_bounds__(256, 3) void k_apply(
    const float* __restrict__ adj, f16* __restrict__ w16,
    const float* __restrict__ ew1, const float* __restrict__ eb1,
    const float* __restrict__ e0w, const float* __restrict__ e0b,
    const float* __restrict__ x3a, const float* __restrict__ x4a,
    const float* __restrict__ wss) {
    __shared__ __align__(16) f16 Et1[Uu * ETS];
    __shared__ __align__(16) float zbuf[4][16 * ZSH];
    int tid = threadIdx.x;
    stageEt(ew1, Et1, tid);
    int l = tid & 63, wv = tid >> 6;
    int r16 = l & 15, q = l >> 4;
    int bn = blockIdx.x * 4 + wv;
    int b = bn / Nn, n = bn % Nn;
    __syncthreads();

    // wn = wold + lrelu((zA + x4)*sc + (c1*sc + sh)), c1 = eb1 + x3a
    float scr[2][8], csr[2][8];
#pragma unroll
    for (int g2 = 0; g2 < 2; ++g2) {
        int ch = g2 * 32 + q * 8;
        float shv[8], c1v[8], ebv[8];
        *(float4*)&scr[g2][0] = *(const float4*)&wss[ch];
        *(float4*)&scr[g2][4] = *(const float4*)&wss[ch + 4];
        *(float4*)&shv[0] = *(const float4*)&wss[64 + ch];
        *(float4*)&shv[4] = *(const float4*)&wss[64 + ch + 4];
        *(float4*)&ebv[0] = *(const float4*)&eb1[ch];
        *(float4*)&ebv[4] = *(const float4*)&eb1[ch + 4];
        *(float4*)&c1v[0] = *(const float4*)&x3a[(size_t)bn * Uu + ch];
        *(float4*)&c1v[4] = *(const float4*)&x3a[(size_t)bn * Uu + ch + 4];
#pragma unroll
        for (int j = 0; j < 8; ++j)
            csr[g2][j] = fmaf(c1v[j] + ebv[j], scr[g2][j], shv[j]);
    }
    float e0r[2][8], e0br[2][8];
    if (FIRST) {
#pragma unroll
        for (int g2 = 0; g2 < 2; ++g2) {
            int ch = g2 * 32 + q * 8;
            *(float4*)&e0r[g2][0] = *(const float4*)&e0w[ch];
            *(float4*)&e0r[g2][4] = *(const float4*)&e0w[ch + 4];
            *(float4*)&e0br[g2][0] = *(const float4*)&e0b[ch];
            *(float4*)&e0br[g2][4] = *(const float4*)&e0b[ch + 4];
        }
    }

    const float* adjrow = adj + (size_t)bn * Nn;
    float* zb = zbuf[wv];

    float advc = 0.f;
    f16x8 A0c = (f16x8){0, 0, 0, 0, 0, 0, 0, 0}, A1c = A0c;
    if (FIRST) {
        advc = adjrow[dstcol(n, r16)];
    } else {
        size_t tb = tbase(bn, 0);
        A0c = ld8(w16 + tb + (size_t)l * 8);
        A1c = ld8(w16 + tb + 512 + (size_t)l * 8);
    }

    for (int mt = 0; mt < 12; ++mt) {  // guard-free rows
        int row = mt * 16 + r16;
        int dst = dstcol(n, row);
        size_t tb = tbase(bn, mt);
        float advn = 0.f;
        f16x8 A0n = (f16x8){0, 0, 0, 0, 0, 0, 0, 0}, A1n = A0n;
        if (FIRST) {
            int rn = row + 16;
            if (rn < NM1) advn = adjrow[dstcol(n, rn)];
        } else {
            size_t tbn = tbase(bn, mt + 1);
            A0n = ld8(w16 + tbn + (size_t)l * 8);
            A1n = ld8(w16 + tbn + 512 + (size_t)l * 8);
        }
        // hoisted x4 row loads (independent of MFMA)
        float x4v[2][8];
        {
            const float* x4r = x4a + (size_t)(b * Nn + dst) * Uu;
            *(float4*)&x4v[0][0] = *(const float4*)(x4r + q * 8);
            *(float4*)&x4v[0][4] = *(const float4*)(x4r + q * 8 + 4);
            *(float4*)&x4v[1][0] = *(const float4*)(x4r + 32 + q * 8);
            *(float4*)&x4v[1][4] = *(const float4*)(x4r + 32 + q * 8 + 4);
        }
        f16x8 A0, A1;
        float wold[2][8];
        if (FIRST) {
            float adv = advc;
#pragma unroll
            for (int j = 0; j < 8; ++j) {
                wold[0][j] = lrelu(fmaf(adv, e0r[0][j], e0br[0][j]));
                wold[1][j] = lrelu(fmaf(adv, e0r[1][j], e0br[1][j]));
                A0[j] = (f16)wold[0][j];
                A1[j] = (f16)wold[1][j];
            }
        } else {
            A0 = A0c;
            A1 = A1c;
#pragma unroll
            for (int j = 0; j < 8; ++j) {
                wold[0][j] = (float)A0[j];
                wold[1][j] = (float)A1[j];
            }
        }
        floatx4 acc[4];
#pragma unroll
        for (int nt = 0; nt < 4; ++nt) {
            f16x8 B0 = *(const f16x8*)&Et1[(nt * 16 + r16) * ETS + q * 8];
            f16x8 B1 = *(const f16x8*)&Et1[(nt * 16 + r16) * ETS + 32 + q * 8];
            acc[nt] = (floatx4){0, 0, 0, 0};
            acc[nt] = __builtin_amdgcn_mfma_f32_16x16x32_f16(A0, B0, acc[nt], 0, 0, 0);
            acc[nt] = __builtin_amdgcn_mfma_f32_16x16x32_f16(A1, B1, acc[nt], 0, 0, 0);
        }
        // C -> A transform, 2 phases (wave-private zbuf, in-order DS)
        float zA[2][8];
#pragma unroll
        for (int rr = 0; rr < 4; ++rr) {
            int zr = q * 4 + rr;
            zb[zr * ZSH + r16] = acc[0][rr];
            zb[zr * ZSH + 16 + r16] = acc[1][rr];
        }
        *(float4*)&zA[0][0] = *(const float4*)&zb[r16 * ZSH + q * 8];
        *(float4*)&zA[0][4] = *(const float4*)&zb[r16 * ZSH + q * 8 + 4];
#pragma unroll
        for (int rr = 0; rr < 4; ++rr) {
            int zr = q * 4 + rr;
            zb[zr * ZSH + r16] = acc[2][rr];
            zb[zr * ZSH + 16 + r16] = acc[3][rr];
        }
        *(float4*)&zA[1][0] = *(const float4*)&zb[r16 * ZSH + q * 8];
        *(float4*)&zA[1][4] = *(const float4*)&zb[r16 * ZSH + q * 8 + 4];

        f16x8 W0, W1;
#pragma unroll
        for (int g2 = 0; g2 < 2; ++g2) {
#pragma unroll
            for (int j = 0; j < 8; ++j) {
                float z = zA[g2][j] + x4v[g2][j];
                float wn = wold[g2][j] + lrelu(fmaf(z, scr[g2][j], csr[g2][j]));
                if (g2 == 0) W0[j] = (f16)wn;
                else W1[j] = (f16)wn;
            }
        }
        st8(w16 + tb + (size_t)l * 8, W0);
        st8(w16 + tb + 512 + (size_t)l * 8, W1);
        advc = advn;
        A0c = A0n;
        A1c = A1n;
    }
    {  // mt = 12 tail, guarded
        const int mt = 12;
        int row = mt * 16 + r16;
        bool rv = row < NM1;
        int dst = dstcol(n, rv ? row : 0);
        size_t tb = tbase(bn, mt);
        f16x8 A0, A1;
        float wold[2][8];
        if (FIRST) {
            float adv = advc;
#pragma unroll
            for (int j = 0; j < 8; ++j) {
                wold[0][j] = lrelu(fmaf(adv, e0r[0][j], e0br[0][j]));
                wold[1][j] = lrelu(fmaf(adv, e0r[1][j], e0br[1][j]));
                A0[j] = (f16)wold[0][j];
                A1[j] = (f16)wold[1][j];
            }
        } else {
            A0 = A0c;
            A1 = A1c;
#pragma unroll
            for (int j = 0; j < 8; ++j) {
                wold[0][j] = (float)A0[j];
                wold[1][j] = (float)A1[j];
            }
        }
        floatx4 acc[4];
#pragma unroll
        for (int nt = 0; nt < 4; ++nt) {
            f16x8 B0 = *(const f16x8*)&Et1[(nt * 16 + r16) * ETS + q * 8];
            f16x8 B1 = *(const f16x8*)&Et1[(nt * 16 + r16) * ETS + 32 + q * 8];
            acc[nt] = (floatx4){0, 0, 0, 0};
            acc[nt] = __builtin_amdgcn_mfma_f32_16x16x32_f16(A0, B0, acc[nt], 0, 0, 0);
            acc[nt] = __builtin_amdgcn_mfma_f32_16x16x32_f16(A1, B1, acc[nt], 0, 0, 0);
        }
        float zA[2][8];
#pragma unroll
        for (int rr = 0; rr < 4; ++rr) {
            int zr = q * 4 + rr;
            zb[zr * ZSH + r16] = acc[0][rr];
            zb[zr * ZSH + 16 + r16] = acc[1][rr];
        }
        *(float4*)&zA[0][0] = *(const float4*)&zb[r16 * ZSH + q * 8];
        *(float4*)&zA[0][4] = *(const float4*)&zb[r16 * ZSH + q * 8 + 4];
#pragma unroll
        for (int rr = 0; rr < 4; ++rr) {
            int zr = q * 4 + rr;
            zb[zr * ZSH + r16] = acc[2][rr];
            zb[zr * ZSH + 16 + r16] = acc[3][rr];
        }
        *(float4*)&zA[1][0] = *(const float4*)&zb[r16 * ZSH + q * 8];
        *(float4*)&zA[1][4] = *(const float4*)&zb[r16 * ZSH + q * 8 + 4];

        float x4v[2][8] = {{0, 0, 0, 0, 0, 0, 0, 0}, {0, 0, 0, 0, 0, 0, 0, 0}};
        if (rv) {
            const float* x4r = x4a + (size_t)(b * Nn + dst) * Uu;
            *(float4*)&x4v[0][0] = *(const float4*)(x4r + q * 8);
            *(float4*)&x4v[0][4] = *(const float4*)(x4r + q * 8 + 4);
            *(float4*)&x4v[1][0] = *(const float4*)(x4r + 32 + q * 8);
            *(float4*)&x4v[1][4] = *(const float4*)(x4r + 32 + q * 8 + 4);
        }
        f16x8 W0, W1;
#pragma unroll
        for (int g2 = 0; g2 < 2; ++g2) {
#pragma unroll
            for (int j = 0; j < 8; ++j) {
                float z = zA[g2][j] + x4v[g2][j];
                float wn = wold[g2][j] + lrelu(fmaf(z, scr[g2][j], csr[g2][j]));
                if (g2 == 0) W0[j] = (f16)wn;
                else W1[j] = (f16)wn;
            }
        }
        st8(w16 + tb + (size_t)l * 8, W0);
        st8(w16 + tb + 512 + (size_t)l * 8, W1);
    }
}

// stats pass (+ optional pool of sig(w)*x2): 4 bn per block (wave-per-bn),
// x4[b] slab in LDS with Et overlay (same geometry rationale as k_first).
template <bool POOL>
__global__ __launch_bounds__(256, 3) void k_p1s(
    const f16* __restrict__ w16, const float* __restrict__ ew2,
    const float* __restrict__ eb2, const float* __restrict__ x3b,
    const float* __restrict__ x4b, const float* __restrict__ x2b,
    float* __restrict__ spread, float* __restrict__ pooled) {
    __shared__ __align__(16) float x4L[Nn * XST];   // 52800 B; head doubles as Et
    f16* Et = (f16*)x4L;
    int tid = threadIdx.x;
    stageEt(ew2, Et, tid);
    int l = tid & 63, wv = tid >> 6;
    int r16 = l & 15, q = l >> 4;
    int bn = blockIdx.x * 4 + wv;
    int b = (blockIdx.x * 4) / Nn;
    int n = bn % Nn;
    __syncthreads();

    f16x8 B0r[4], B1r[4];
    float c2v[4];
#pragma unroll
    for (int nt = 0; nt < 4; ++nt) {
        B0r[nt] = *(const f16x8*)&Et[(nt * 16 + r16) * ETS + q * 8];
        B1r[nt] = *(const f16x8*)&Et[(nt * 16 + r16) * ETS + 32 + q * 8];
        int u = nt * 16 + r16;
        c2v[nt] = eb2[u] + x3b[(size_t)bn * Uu + u];
    }
    __syncthreads();  // Et reads done; overwrite with slab
    {
        const float* src = x4b + (size_t)b * Nn * Uu;
        for (int i = tid; i < Nn * 16; i += 256) {
            int row = i >> 4, c4 = (i & 15) << 2;
            float4 v = *(const float4*)(src + row * Uu + c4);
            float* d = &x4L[row * XST + c4];
            ((float2*)d)[0] = make_float2(v.x, v.y);
            ((float2*)d)[1] = make_float2(v.z, v.w);
        }
    }
    __syncthreads();

    float sum[4] = {0, 0, 0, 0}, sq[4] = {0, 0, 0, 0};
    float pm[2][8];
    if (POOL) {
#pragma unroll
        for (int g2 = 0; g2 < 2; ++g2)
#pragma unroll
            for (int j = 0; j < 8; ++j) pm[g2][j] = -3.402823e38f;
    }

    f16x8 A0c, A1c;
    {
        size_t tb = tbase(bn, 0);
        A0c = ld8(w16 + tb + (size_t)l * 8);
        A1c = ld8(w16 + tb + 512 + (size_t)l * 8);
    }

    for (int mt = 0; mt < 12; ++mt) {  // guard-free
        int row = mt * 16 + r16;
        int dst = dstcol(n, row);
        f16x8 A0n, A1n;
        {
            size_t tbn = tbase(bn, mt + 1);
            A0n = ld8(w16 + tbn + (size_t)l * 8);
            A1n = ld8(w16 + tbn + 512 + (size_t)l * 8);
        }
        // stats gather from LDS slab
        float xs[4][4];
#pragma unroll
        for (int rr = 0; rr < 4; ++rr) {
            const float* x4r = x4L + dstcol(n, mt * 16 + q * 4 + rr) * XST;
#pragma unroll
            for (int nt = 0; nt < 4; ++nt) xs[rr][nt] = x4r[nt * 16 + r16];
        }
        float xv[2][8];
        if (POOL) {
            const float* x2r = x2b + (size_t)(b * Nn + dst) * Uu;
            *(float4*)&xv[0][0] = *(const float4*)(x2r + q * 8);
            *(float4*)&xv[0][4] = *(const float4*)(x2r + q * 8 + 4);
            *(float4*)&xv[1][0] = *(const float4*)(x2r + 32 + q * 8);
            *(float4*)&xv[1][4] = *(const float4*)(x2r + 32 + q * 8 + 4);
        }
        f16x8 A0 = A0c, A1 = A1c;
        floatx4 acc[4];
#pragma unroll
        for (int nt = 0; nt < 4; ++nt) {
            acc[nt] = (floatx4){0, 0, 0, 0};
            acc[nt] = __builtin_amdgcn_mfma_f32_16x16x32_f16(A0, B0r[nt], acc[nt], 0, 0, 0);
            acc[nt] = __builtin_amdgcn_mfma_f32_16x16x32_f16(A1, B1r[nt], acc[nt], 0, 0, 0);
        }
#pragma unroll
        for (int rr = 0; rr < 4; ++rr)
#pragma unroll
            for (int nt = 0; nt < 4; ++nt) {
                float z = acc[nt][rr] + c2v[nt] + xs[rr][nt];
                sum[nt] += z;
                sq[nt] = fmaf(z, z, sq[nt]);
            }
        if (POOL) {
#pragma unroll
            for (int g2 = 0; g2 < 2; ++g2)
#pragma unroll
                for (int j = 0; j < 8; ++j) {
                    float wv_ = (float)(g2 == 0 ? A0[j] : A1[j]);
                    pm[g2][j] = fmaxf(pm[g2][j], sigm(wv_) * xv[g2][j]);
                }
        }
        A0c = A0n;
        A1c = A1n;
    }
    {  // mt = 12 tail, guarded
        const int mt = 12;
        int row = mt * 16 + r16;
        bool rv = row < NM1;
        f16x8 A0 = A0c, A1 = A1c;
        floatx4 acc[4];
#pragma unroll
        for (int nt = 0; nt < 4; ++nt) {
            acc[nt] = (floatx4){0, 0, 0, 0};
            acc[nt] = __builtin_amdgcn_mfma_f32_16x16x32_f16(A0, B0r[nt], acc[nt], 0, 0, 0);
            acc[nt] = __builtin_amdgcn_mfma_f32_16x16x32_f16(A1, B1r[nt], acc[nt], 0, 0, 0);
        }
#pragma unroll
        for (int rr = 0; rr < 4; ++rr) {
            int k = mt * 16 + q * 4 + rr;
            if (k < NM1) {
                const float* x4r = x4L + dstcol(n, k) * XST;
#pragma unroll
                for (int nt = 0; nt < 4; ++nt) {
                    float z = acc[nt][rr] + c2v[nt] + x4r[nt * 16 + r16];
                    sum[nt] += z;
                    sq[nt] = fmaf(z, z, sq[nt]);
                }
            }
        }
        if (POOL && rv) {
            int dst = dstcol(n, row);
            const float* x2r = x2b + (size_t)(b * Nn + dst) * Uu;
#pragma unroll
            for (int g2 = 0; g2 < 2; ++g2) {
                float xv[8];
                *(float4*)&xv[0] = *(const float4*)(x2r + g2 * 32 + q * 8);
                *(float4*)&xv[4] = *(const float4*)(x2r + g2 * 32 + q * 8 + 4);
#pragma unroll
                for (int j = 0; j < 8; ++j) {
                    float wv_ = (float)(g2 == 0 ? A0[j] : A1[j]);
                    pm[g2][j] = fmaxf(pm[g2][j], sigm(wv_) * xv[j]);
                }
            }
        }
    }
#pragma unroll
    for (int nt = 0; nt < 4; ++nt) {
        sum[nt] += __shfl_xor(sum[nt], 16, 64);
        sum[nt] += __shfl_xor(sum[nt], 32, 64);
        sq[nt] += __shfl_xor(sq[nt], 16, 64);
        sq[nt] += __shfl_xor(sq[nt], 32, 64);
    }
    float* sp = spread + (size_t)(bn & (SPREAD - 1)) * 128;
    if (l < 16) {
#pragma unroll
        for (int nt = 0; nt < 4; ++nt) {
            atomicAdd(&sp[nt * 16 + l], sum[nt]);
            atomicAdd(&sp[64 + nt * 16 + l], sq[nt]);
        }
    }
    if (POOL) {
#pragma unroll
        for (int g2 = 0; g2 < 2; ++g2)
#pragma unroll
            for (int j = 0; j < 8; ++j) {
                float v = pm[g2][j];
                v = fmaxf(v, __shfl_xor(v, 1, 64));
                v = fmaxf(v, __shfl_xor(v, 2, 64));
                v = fmaxf(v, __shfl_xor(v, 4, 64));
                v = fmaxf(v, __shfl_xor(v, 8, 64));
                pm[g2][j] = v;
            }
        if (r16 == 0) {
#pragma unroll
            for (int g2 = 0; g2 < 2; ++g2)
#pragma unroll
                for (int j = 0; j < 8; ++j)
                    pooled[(size_t)bn * Uu + g2 * 32 + q * 8 + j] = pm[g2][j];
        }
    }
}

// last: apply BN(2)+residual, dot with e_lin1, scatter to out; wave-per-bn (R7 form)
__global__ __launch_bounds__(256, 3) void k_last(
    const f16* __restrict__ w16, const float* __restrict__ ew1,
    const float* __restrict__ eb1, const float* __restrict__ x3a,
    const float* __restrict__ x4a, const float* __restrict__ wss,
    const float* __restrict__ elw, const float* __restrict__ elb,
    float* __restrict__ out) {
    __shared__ __align__(16) f16 Et1[Uu * ETS];
    __shared__ __align__(16) float zbuf[4][16 * ZSH];
    int tid = threadIdx.x;
    stageEt(ew1, Et1, tid);
    int l = tid & 63, wv = tid >> 6;
    int r16 = l & 15, q = l >> 4;
    int bn = blockIdx.x * 4 + wv;
    int b = bn / Nn, n = bn % Nn;
    __syncthreads();

    float scr[2][8], csr[2][8], elr[2][8];
#pragma unroll
    for (int g2 = 0; g2 < 2; ++g2) {
        int ch = g2 * 32 + q * 8;
        float shv[8], c1v[8], ebv[8];
        *(float4*)&scr[g2][0] = *(const float4*)&wss[ch];
        *(float4*)&scr[g2][4] = *(const float4*)&wss[ch + 4];
        *(float4*)&shv[0] = *(const float4*)&wss[64 + ch];
        *(float4*)&shv[4] = *(const float4*)&wss[64 + ch + 4];
        *(float4*)&ebv[0] = *(const float4*)&eb1[ch];
        *(float4*)&ebv[4] = *(const float4*)&eb1[ch + 4];
        *(float4*)&c1v[0] = *(const float4*)&x3a[(size_t)bn * Uu + ch];
        *(float4*)&c1v[4] = *(const float4*)&x3a[(size_t)bn * Uu + ch + 4];
        *(float4*)&elr[g2][0] = *(const float4*)&elw[ch];
        *(float4*)&elr[g2][4] = *(const float4*)&elw[ch + 4];
#pragma unroll
        for (int j = 0; j < 8; ++j)
            csr[g2][j] = fmaf(c1v[j] + ebv[j], scr[g2][j], shv[j]);
    }

    float elb0 = elb[0];
    float* zb = zbuf[wv];

    f16x8 A0c, A1c;
    {
        size_t tb = tbase(bn, 0);
        A0c = ld8(w16 + tb + (size_t)l * 8);
        A1c = ld8(w16 + tb + 512 + (size_t)l * 8);
    }

    for (int mt = 0; mt < 12; ++mt) {  // guard-free
        int row = mt * 16 + r16;
        int dst = dstcol(n, row);
        f16x8 A0n, A1n;
        {
            size_t tbn = tbase(bn, mt + 1);
            A0n = ld8(w16 + tbn + (size_t)l * 8);
            A1n = ld8(w16 + tbn + 512 + (size_t)l * 8);
        }
        // hoisted x4 loads
        float x4v[2][8];
        {
            const float* x4r = x4a + (size_t)(b * Nn + dst) * Uu;
            *(float4*)&x4v[0][0] = *(const float4*)(x4r + q * 8);
            *(float4*)&x4v[0][4] = *(const float4*)(x4r + q * 8 + 4);
            *(float4*)&x4v[1][0] = *(const float4*)(x4r + 32 + q * 8);
            *(float4*)&x4v[1][4] = *(const float4*)(x4r + 32 + q * 8 + 4);
        }
        f16x8 A0 = A0c, A1 = A1c;
        float wold[2][8];
#pragma unroll
        for (int j = 0; j < 8; ++j) {
            wold[0][j] = (float)A0[j];
            wold[1][j] = (float)A1[j];
        }
        floatx4 acc[4];
#pragma unroll
        for (int nt = 0; nt < 4; ++nt) {
            f16x8 B0 = *(const f16x8*)&Et1[(nt * 16 + r16) * ETS + q * 8];
            f16x8 B1 = *(const f16x8*)&Et1[(nt * 16 + r16) * ETS + 32 + q * 8];
            acc[nt] = (floatx4){0, 0, 0, 0};
            acc[nt] = __builtin_amdgcn_mfma_f32_16x16x32_f16(A0, B0, acc[nt], 0, 0, 0);
            acc[nt] = __builtin_amdgcn_mfma_f32_16x16x32_f16(A1, B1, acc[nt], 0, 0, 0);
        }
        float zA[2][8];
#pragma unroll
        for (int rr = 0; rr < 4; ++rr) {
            int zr = q * 4 + rr;
            zb[zr * ZSH + r16] = acc[0][rr];
            zb[zr * ZSH + 16 + r16] = acc[1][rr];
        }
        *(float4*)&zA[0][0] = *(const float4*)&zb[r16 * ZSH + q * 8];
        *(float4*)&zA[0][4] = *(const float4*)&zb[r16 * ZSH + q * 8 + 4];
#pragma unroll
        for (int rr = 0; rr < 4; ++rr) {
            int zr = q * 4 + rr;
            zb[zr * ZSH + r16] = acc[2][rr];
            zb[zr * ZSH + 16 + r16] = acc[3][rr];
        }
        *(float4*)&zA[1][0] = *(const float4*)&zb[r16 * ZSH + q * 8];
        *(float4*)&zA[1][4] = *(const float4*)&zb[r16 * ZSH + q * 8 + 4];

        float t = 0.f;
#pragma unroll
        for (int g2 = 0; g2 < 2; ++g2) {
#pragma unroll
            for (int j = 0; j < 8; ++j) {
                float z = zA[g2][j] + x4v[g2][j];
                float wn = wold[g2][j] + lrelu(fmaf(z, scr[g2][j], csr[g2][j]));
                t = fmaf(wn, elr[g2][j], t);
            }
        }
        t += __shfl_xor(t, 16, 64);
        t += __shfl_xor(t, 32, 64);
        if (q == 0) out[(size_t)bn * Nn + dst] = t + elb0;
        A0c = A0n;
        A1c = A1n;
    }
    {  // mt = 12 tail, guarded
        const int mt = 12;
        int row = mt * 16 + r16;
        bool rv = row < NM1;
        int dst = dstcol(n, rv ? row : 0);
        f16x8 A0 = A0c, A1 = A1c;
        float wold[2][8];
#pragma unroll
        for (int j = 0; j < 8; ++j) {
            wold[0][j] = (float)A0[j];
            wold[1][j] = (float)A1[j];
        }
        floatx4 acc[4];
#pragma unroll
        for (int nt = 0; nt < 4; ++nt) {
            f16x8 B0 = *(const f16x8*)&Et1[(nt * 16 + r16) * ETS + q * 8];
            f16x8 B1 = *(const f16x8*)&Et1[(nt * 16 + r16) * ETS + 32 + q * 8];
            acc[nt] = (floatx4){0, 0, 0, 0};
            acc[nt] = __builtin_amdgcn_mfma_f32_16x16x32_f16(A0, B0, acc[nt], 0, 0, 0);
            acc[nt] = __builtin_amdgcn_mfma_f32_16x16x32_f16(A1, B1, acc[nt], 0, 0, 0);
        }
        float zA[2][8];
#pragma unroll
        for (int rr = 0; rr < 4; ++rr) {
            int zr = q * 4 + rr;
            zb[zr * ZSH + r16] = acc[0][rr];
            zb[zr * ZSH + 16 + r16] = acc[1][rr];
        }
        *(float4*)&zA[0][0] = *(const float4*)&zb[r16 * ZSH + q * 8];
        *(float4*)&zA[0][4] = *(const float4*)&zb[r16 * ZSH + q * 8 + 4];
#pragma unroll
        for (int rr = 0; rr < 4; ++rr) {
            int zr = q * 4 + rr;
            zb[zr * ZSH + r16] = acc[2][rr];
            zb[zr * ZSH + 16 + r16] = acc[3][rr];
        }
        *(float4*)&zA[1][0] = *(const float4*)&zb[r16 * ZSH + q * 8];
        *(float4*)&zA[1][4] = *(const float4*)&zb[r16 * ZSH + q * 8 + 4];

        float x4v[2][8] = {{0, 0, 0, 0, 0, 0, 0, 0}, {0, 0, 0, 0, 0, 0, 0, 0}};
        if (rv) {
            const float* x4r = x4a + (size_t)(b * Nn + dst) * Uu;
            *(float4*)&x4v[0][0] = *(const float4*)(x4r + q * 8);
            *(float4*)&x4v[0][4] = *(const float4*)(x4r + q * 8 + 4);
            *(float4*)&x4v[1][0] = *(const float4*)(x4r + 32 + q * 8);
            *(float4*)&x4v[1][4] = *(const float4*)(x4r + 32 + q * 8 + 4);
        }
        float t = 0.f;
#pragma unroll
        for (int g2 = 0; g2 < 2; ++g2) {
#pragma unroll
            for (int j = 0; j < 8; ++j) {
                float z = zA[g2][j] + x4v[g2][j];
                float wn = wold[g2][j] + lrelu(fmaf(z, scr[g2][j], csr[g2][j]));
                t = fmaf(wn, elr[g2][j], t);
            }
        }
        t += __shfl_xor(t, 16, 64);
        t += __shfl_xor(t, 32, 64);
        if (q == 0 && rv) out[(size_t)bn * Nn + dst] = t + elb0;
    }
    if (l == 0) out[(size_t)bn * Nn + n] = 0.f;
}

// finw (block 64) + hup (blocks 0..63)
__global__ void k_mid(const float* __restrict__ spread, const float* __restrict__ eg,
                      const float* __restrict__ ebb, float* __restrict__ wss,
                      const float* __restrict__ x1, const float* __restrict__ pooled,
                      const float* __restrict__ vg, const float* __restrict__ vbb,
                      float* __restrict__ h) {
    if (blockIdx.x == 64) {
        int u = threadIdx.x;
        if (u < 64) {
            float s = 0.f, sqv = 0.f;
            for (int p = 0; p < SPREAD; ++p) {
                s += spread[p * 128 + u];
                sqv += spread[p * 128 + 64 + u];
            }
            const float Mf = (float)((size_t)Bb * Nn * NM1);
            float mean = s / Mf;
            float var = fmaxf(sqv / Mf - mean * mean, 0.f);
            float inv = rsqrtf(var + EPSBN);
            float scale = eg[u] * inv;
            wss[u] = scale;
            wss[64 + u] = ebb[u] - mean * scale;
        }
        return;
    }
    __shared__ float red[256], red2[256];
    int ch = blockIdx.x;
    int t = threadIdx.x;
    float s = 0.f, sqv = 0.f;
    for (int bn = t; bn < Bb * Nn; bn += 256) {
        float v = x1[bn * Uu + ch] + pooled[bn * Uu + ch];
        s += v;
        sqv = fmaf(v, v, sqv);
    }
    red[t] = s;
    red2[t] = sqv;
    __syncthreads();
    for (int off = 128; off; off >>= 1) {
        if (t < off) {
            red[t] += red[t + off];
            red2[t] += red2[t + off];
        }
        __syncthreads();
    }
    const float Mf = (float)(Bb * Nn);
    float mean = red[0] / Mf;
    float var = fmaxf(red2[0] / Mf - mean * mean, 0.f);
    float inv = rsqrtf(var + EPSBN);
    float scale = vg[ch] * inv;
    float shift = vbb[ch] - mean * scale;
    for (int bn = t; bn < Bb * Nn; bn += 256) {
        float v = x1[bn * Uu + ch] + pooled[bn * Uu + ch];
        h[bn * Uu + ch] += lrelu(fmaf(v, scale, shift));
    }
}

__global__ void k_finw(const float* __restrict__ spread, const float* __restrict__ g,
                       const float* __restrict__ bb, float* __restrict__ wss) {
    int u = threadIdx.x;
    float s = 0.f, sq = 0.f;
    for (int p = 0; p < SPREAD; ++p) {
        s += spread[p * 128 + u];
        sq += spread[p * 128 + 64 + u];
    }
    const float Mf = (float)((size_t)Bb * Nn * NM1);
    float mean = s / Mf;
    float var = fmaxf(sq / Mf - mean * mean, 0.f);
    float inv = rsqrtf(var + EPSBN);
    float scale = g[u] * inv;
    wss[u] = scale;
    wss[64 + u] = bb[u] - mean * scale;
}

extern "C" void kernel_launch(void* const* d_in, const int* in_sizes, int n_in,
                              void* d_out, int out_size, void* d_ws, size_t ws_size,
                              hipStream_t stream) {
    const float* x = (const float*)d_in[0];
    const float* adj = (const float*)d_in[1];
    const float* vl0w = (const float*)d_in[2];
    const float* vl0b = (const float*)d_in[3];
    const float* vw1 = (const float*)d_in[4];
    const float* vb1 = (const float*)d_in[5];
    const float* vw2 = (const float*)d_in[6];
    const float* vb2 = (const float*)d_in[7];
    const float* vw3 = (const float*)d_in[8];
    const float* vb3 = (const float*)d_in[9];
    const float* vw4 = (const float*)d_in[10];
    const float* vb4 = (const float*)d_in[11];
    const float* vbng = (const float*)d_in[12];
    const float* vbnb = (const float*)d_in[13];
    const float* e0w = (const float*)d_in[14];
    const float* e0b = (const float*)d_in[15];
    const float* ew = (const float*)d_in[16];
    const float* eb = (const float*)d_in[17];
    const float* ebng = (const float*)d_in[18];
    const float* ebnb = (const float*)d_in[19];
    const float* elw = (const float*)d_in[20];
    const float* elb = (const float*)d_in[21];
    float* out = (float*)d_out;

    f16* w16 = (f16*)d_ws;                      // 3200*13*1024 = 42,598,400 f16
    float* fb = (float*)d_ws + 21299200;
    const size_t NV = 204800;
    float* h = fb;
    float* xv1[3] = {fb + NV, fb + 2 * NV, fb + 3 * NV};
    float* xv2[3] = {fb + 4 * NV, fb + 5 * NV, fb + 6 * NV};
    float* xv3[3] = {fb + 7 * NV, fb + 8 * NV, fb + 9 * NV};
    float* xv4[3] = {fb + 10 * NV, fb + 11 * NV, fb + 12 * NV};
    float* pooled = fb + 13 * NV;
    float* spread = fb + 14 * NV;               // SPREAD*128
    float* wss = spread + SPREAD * 128;         // 128

    const int GRID4 = (Bb * Nn) / 4;  // 800 blocks, 4 bn per block (1/wave)

    // layer 0
    k_xvec<true><<<GRID4, 256, 0, stream>>>(x, vl0w, vl0b, h, vw1, vb1, vw2, vb2,
                                            vw3, vb3, vw4, vb4, xv1[0], xv2[0],
                                            xv3[0], xv4[0], spread);
    k_first<<<GRID4, 256, 0, stream>>>(adj, ew, eb, e0w, e0b, xv2[0], xv3[0], xv4[0],
                                       pooled, spread);
    k_mid<<<65, 256, 0, stream>>>(spread, ebng, ebnb, wss, xv1[0], pooled, vbng,
                                  vbnb, h);
    // layer 1
    k_xvec<false><<<GRID4, 256, 0, stream>>>(x, vl0w, vl0b, h, vw1 + 4096, vb1 + 64,
                                             vw2 + 4096, vb2 + 64, vw3 + 4096,
                                             vb3 + 64, vw4 + 4096, vb4 + 64, xv1[1],
                                             xv2[1], xv3[1], xv4[1], spread);
    k_apply<true><<<GRID4, 256, 0, stream>>>(adj, w16, ew, eb, e0w, e0b, xv3[0],
                                             xv4[0], wss);
    k_p1s<true><<<GRID4, 256, 0, stream>>>(w16, ew + 4096, eb + 64, xv3[1], xv4[1],
                                           xv2[1], spread, pooled);
    k_mid<<<65, 256, 0, stream>>>(spread, ebng + 64, ebnb + 64, wss, xv1[1], pooled,
                                  vbng + 64, vbnb + 64, h);
    // layer 2 (h-path after layer 2 is dead: no pool, no h update)
    k_xvec<false><<<GRID4, 256, 0, stream>>>(x, vl0w, vl0b, h, vw1 + 8192, vb1 + 128,
                                             vw2 + 8192, vb2 + 128, vw3 + 8192,
                                             vb3 + 128, vw4 + 8192, vb4 + 128,
                                             xv1[2], xv2[2], xv3[2], xv4[2], spread);
    k_apply<false><<<GRID4, 256, 0, stream>>>(adj, w16, ew + 4096, eb + 64, e0w, e0b,
                                              xv3[1], xv4[1], wss);
    k_p1s<false><<<GRID4, 256, 0, stream>>>(w16, ew + 8192, eb + 128, xv3[2], xv4[2],
                                            xv2[2], spread, pooled);
    k_finw<<<1, 64, 0, stream>>>(spread, ebng + 128, ebnb + 128, wss);
    k_last<<<GRID4, 256, 0, stream>>>(w16, ew + 8192, eb + 128, xv3[2], xv4[2], wss,
                                      elw, elb, out);
}

// Round 10
// 373.206 us; speedup vs baseline: 1.0222x; 1.0222x over previous
//
#include <hip/hip_runtime.h>

#define Bb 16
#define Nn 200
#define NM1 199
#define Uu 64
#define EPSBN 1e-5f
#define SLOPE 0.01f
#define SPREAD 64
#define ETS 72   // f16 elems per Et row (64 + 8 pad)
#define ZSH 36   // f32 elems per zbuf row (32 + 4 pad), 2-phase transform

typedef _Float16 f16;
typedef __attribute__((ext_vector_type(8))) _Float16 f16x8;
typedef __attribute__((ext_vector_type(2))) _Float16 f16x2;
typedef __attribute__((ext_vector_type(4))) float floatx4;

// w16 tile layout: per (bn, mt) a 1024-f16 tile; chunk l (16 B) == lane l's
// A-fragment (KB0 at +0, KB1 at +512 elems). Wave-contiguous 1 KB per access.
__device__ __forceinline__ size_t tbase(int bn, int mt) {
    return ((size_t)bn * 13 + mt) * 1024;
}

// slope < 1  =>  lrelu(v) == max(v, slope*v)
__device__ __forceinline__ float lrelu(float v) { return fmaxf(v, SLOPE * v); }
__device__ __forceinline__ int dstcol(int n, int k) { return k < n ? k : k + 1; }
// v_rcp_f32 approx (~1 ulp) instead of IEEE div
__device__ __forceinline__ float sigm(float v) {
    return __builtin_amdgcn_rcpf(1.f + __expf(-v));
}

// plain (cacheable) w16 access: 85 MB fits L3
__device__ __forceinline__ f16x8 ld8(const f16* p) { return *(const f16x8*)p; }
__device__ __forceinline__ void st8(f16* p, f16x8 v) { *(f16x8*)p = v; }

// 256-thread variant (k_apply / k_last)
__device__ __forceinline__ void stageEt(const float* __restrict__ ew, f16* Et, int tid) {
    int u = tid & 63, g = tid >> 6;
#pragma unroll
    for (int pp = 0; pp < 8; ++pp) {
        int jp = g + pp * 4;
        f16x2 pk;
        pk.x = (f16)ew[(2 * jp) * Uu + u];
        pk.y = (f16)ew[(2 * jp + 1) * Uu + u];
        *(f16x2*)&Et[u * ETS + 2 * jp] = pk;
    }
}

// 512-thread variant (k_first / k_p1s)
__device__ __forceinline__ void stageEt512(const float* __restrict__ ew, f16* Et, int tid) {
    int u = tid & 63, g = tid >> 6;  // g in 0..7
#pragma unroll
    for (int pp = 0; pp < 4; ++pp) {
        int jp = g + pp * 8;
        f16x2 pk;
        pk.x = (f16)ew[(2 * jp) * Uu + u];
        pk.y = (f16)ew[(2 * jp + 1) * Uu + u];
        *(f16x2*)&Et[u * ETS + 2 * jp] = pk;
    }
}

// x-vec projections, 4 bn per block (one per wave); L0 also computes h from x
template <bool L0>
__global__ void k_xvec(const float* __restrict__ xin, const float* __restrict__ l0w,
                       const float* __restrict__ l0b, float* __restrict__ h,
                       const float* __restrict__ w1, const float* __restrict__ b1,
                       const float* __restrict__ w2, const float* __restrict__ b2,
                       const float* __restrict__ w3, const float* __restrict__ b3,
                       const float* __restrict__ w4, const float* __restrict__ b4,
                       float* __restrict__ x1, float* __restrict__ x2,
                       float* __restrict__ x3, float* __restrict__ x4,
                       float* __restrict__ spread) {
    __shared__ float hrow[4][Uu];
    int tid = threadIdx.x;
    int u = tid & 63, wv = tid >> 6;
    int bn = blockIdx.x * 4 + wv;
    if (blockIdx.x == 0) {
        for (int t = tid; t < SPREAD * 128; t += 256) spread[t] = 0.f;
    }
    float v;
    if (L0) {
        v = fmaf(xin[bn * 2], l0w[u], fmaf(xin[bn * 2 + 1], l0w[Uu + u], l0b[u]));
        v = lrelu(v);
        h[(size_t)bn * Uu + u] = v;
    } else {
        v = h[(size_t)bn * Uu + u];
    }
    hrow[wv][u] = v;  // wave-private LDS: in-order within wave, no barrier
    float a1 = b1[u], a2 = b2[u], a3 = b3[u], a4 = b4[u];
#pragma unroll 8
    for (int j = 0; j < Uu; ++j) {
        float hv = hrow[wv][j];
        a1 = fmaf(hv, w1[j * Uu + u], a1);
        a2 = fmaf(hv, w2[j * Uu + u], a2);
        a3 = fmaf(hv, w3[j * Uu + u], a3);
        a4 = fmaf(hv, w4[j * Uu + u], a4);
    }
    x1[(size_t)bn * Uu + u] = a1;
    x2[(size_t)bn * Uu + u] = a2;
    x3[(size_t)bn * Uu + u] = a3;
    x4[(size_t)bn * Uu + u] = a4;
}

// layer-0 stats + pooled; 8 bn per block (one per wave), 512 threads.
// The x4[b] slab (200x64 f32 = 51.2 KB; b is block-uniform since 200%8==0)
// is staged in LDS so the divergent 16-way stats gather is ds_read, not
// global -- removes the loop's only exposed global latency.
__global__ __launch_bounds__(512, 2) void k_first(
    const float* __restrict__ adj,
    const float* __restrict__ ew1, const float* __restrict__ eb1,
    const float* __restrict__ e0w, const float* __restrict__ e0b,
    const float* __restrict__ x2a, const float* __restrict__ x3a,
    const float* __restrict__ x4a,
    float* __restrict__ pooled, float* __restrict__ spread) {
    __shared__ __align__(16) f16 Et[Uu * ETS];      // 9216 B
    __shared__ __align__(16) float x4L[Nn * Uu];    // 51200 B
    int tid = threadIdx.x;
    stageEt512(ew1, Et, tid);
    int l = tid & 63, wv = tid >> 6;
    int r16 = l & 15, q = l >> 4;
    int bn = blockIdx.x * 8 + wv;
    int b = (blockIdx.x * 8) / Nn;
    int n = bn % Nn;
    {
        const float4* src = (const float4*)(x4a + (size_t)b * Nn * Uu);
        float4* dstp = (float4*)x4L;
        for (int i = tid; i < (Nn * Uu) / 4; i += 512) dstp[i] = src[i];
    }
    __syncthreads();

    f16x8 B0r[4], B1r[4];
    float c2v[4];
#pragma unroll
    for (int nt = 0; nt < 4; ++nt) {
        B0r[nt] = *(const f16x8*)&Et[(nt * 16 + r16) * ETS + q * 8];
        B1r[nt] = *(const f16x8*)&Et[(nt * 16 + r16) * ETS + 32 + q * 8];
        int u = nt * 16 + r16;
        c2v[nt] = eb1[u] + x3a[(size_t)bn * Uu + u];
    }

    float e0r[2][8], e0br[2][8];
#pragma unroll
    for (int g2 = 0; g2 < 2; ++g2) {
        int ch = g2 * 32 + q * 8;
        *(float4*)&e0r[g2][0] = *(const float4*)&e0w[ch];
        *(float4*)&e0r[g2][4] = *(const float4*)&e0w[ch + 4];
        *(float4*)&e0br[g2][0] = *(const float4*)&e0b[ch];
        *(float4*)&e0br[g2][4] = *(const float4*)&e0b[ch + 4];
    }

    const float* adjrow = adj + (size_t)bn * Nn;
    float sum[4] = {0, 0, 0, 0}, sq[4] = {0, 0, 0, 0};
    float pm[2][8];
#pragma unroll
    for (int g2 = 0; g2 < 2; ++g2)
#pragma unroll
        for (int j = 0; j < 8; ++j) pm[g2][j] = -3.402823e38f;

    float advc = adjrow[dstcol(n, r16)];
    for (int mt = 0; mt < 12; ++mt) {  // guard-free: all rows/k < NM1
        int row = mt * 16 + r16;
        int dst = dstcol(n, row);
        float advn = 0.f;
        {
            int rn = row + 16;
            if (rn < NM1) advn = adjrow[dstcol(n, rn)];
        }
        // stats gather now from LDS slab (2-way bank aliasing = free)
        float xs[4][4];
#pragma unroll
        for (int rr = 0; rr < 4; ++rr) {
            const float* x4r = x4L + dstcol(n, mt * 16 + q * 4 + rr) * Uu;
#pragma unroll
            for (int nt = 0; nt < 4; ++nt) xs[rr][nt] = x4r[nt * 16 + r16];
        }
        float xv[2][8];
        const float* x2r = x2a + (size_t)(b * Nn + dst) * Uu;
        *(float4*)&xv[0][0] = *(const float4*)(x2r + q * 8);
        *(float4*)&xv[0][4] = *(const float4*)(x2r + q * 8 + 4);
        *(float4*)&xv[1][0] = *(const float4*)(x2r + 32 + q * 8);
        *(float4*)&xv[1][4] = *(const float4*)(x2r + 32 + q * 8 + 4);

        float adv = advc;
        float w0[2][8];
        f16x8 A0, A1;
#pragma unroll
        for (int j = 0; j < 8; ++j) {
            w0[0][j] = lrelu(fmaf(adv, e0r[0][j], e0br[0][j]));
            w0[1][j] = lrelu(fmaf(adv, e0r[1][j], e0br[1][j]));
            A0[j] = (f16)w0[0][j];
            A1[j] = (f16)w0[1][j];
        }
        floatx4 acc[4];
#pragma unroll
        for (int nt = 0; nt < 4; ++nt) {
            acc[nt] = (floatx4){0, 0, 0, 0};
            acc[nt] = __builtin_amdgcn_mfma_f32_16x16x32_f16(A0, B0r[nt], acc[nt], 0, 0, 0);
            acc[nt] = __builtin_amdgcn_mfma_f32_16x16x32_f16(A1, B1r[nt], acc[nt], 0, 0, 0);
        }
#pragma unroll
        for (int rr = 0; rr < 4; ++rr)
#pragma unroll
            for (int nt = 0; nt < 4; ++nt) {
                float z = acc[nt][rr] + c2v[nt] + xs[rr][nt];
                sum[nt] += z;
                sq[nt] = fmaf(z, z, sq[nt]);
            }
#pragma unroll
        for (int g2 = 0; g2 < 2; ++g2)
#pragma unroll
            for (int j = 0; j < 8; ++j)
                pm[g2][j] = fmaxf(pm[g2][j], sigm(w0[g2][j]) * xv[g2][j]);
        advc = advn;
    }
    {  // mt = 12 tail, guarded
        const int mt = 12;
        int row = mt * 16 + r16;
        bool rv = row < NM1;
        int dst = dstcol(n, rv ? row : 0);
        float adv = advc;
        float w0[2][8];
        f16x8 A0, A1;
#pragma unroll
        for (int j = 0; j < 8; ++j) {
            w0[0][j] = lrelu(fmaf(adv, e0r[0][j], e0br[0][j]));
            w0[1][j] = lrelu(fmaf(adv, e0r[1][j], e0br[1][j]));
            A0[j] = (f16)w0[0][j];
            A1[j] = (f16)w0[1][j];
        }
        floatx4 acc[4];
#pragma unroll
        for (int nt = 0; nt < 4; ++nt) {
            acc[nt] = (floatx4){0, 0, 0, 0};
            acc[nt] = __builtin_amdgcn_mfma_f32_16x16x32_f16(A0, B0r[nt], acc[nt], 0, 0, 0);
            acc[nt] = __builtin_amdgcn_mfma_f32_16x16x32_f16(A1, B1r[nt], acc[nt], 0, 0, 0);
        }
#pragma unroll
        for (int rr = 0; rr < 4; ++rr) {
            int k = mt * 16 + q * 4 + rr;
            if (k < NM1) {
                const float* x4r = x4L + dstcol(n, k) * Uu;
#pragma unroll
                for (int nt = 0; nt < 4; ++nt) {
                    float z = acc[nt][rr] + c2v[nt] + x4r[nt * 16 + r16];
                    sum[nt] += z;
                    sq[nt] = fmaf(z, z, sq[nt]);
                }
            }
        }
        if (rv) {
            const float* x2r = x2a + (size_t)(b * Nn + dst) * Uu;
#pragma unroll
            for (int g2 = 0; g2 < 2; ++g2) {
                float xv[8];
                *(float4*)&xv[0] = *(const float4*)(x2r + g2 * 32 + q * 8);
                *(float4*)&xv[4] = *(const float4*)(x2r + g2 * 32 + q * 8 + 4);
#pragma unroll
                for (int j = 0; j < 8; ++j)
                    pm[g2][j] = fmaxf(pm[g2][j], sigm(w0[g2][j]) * xv[j]);
            }
        }
    }
#pragma unroll
    for (int nt = 0; nt < 4; ++nt) {
        sum[nt] += __shfl_xor(sum[nt], 16, 64);
        sum[nt] += __shfl_xor(sum[nt], 32, 64);
        sq[nt] += __shfl_xor(sq[nt], 16, 64);
        sq[nt] += __shfl_xor(sq[nt], 32, 64);
    }
    float* sp = spread + (size_t)(bn & (SPREAD - 1)) * 128;
    if (l < 16) {
#pragma unroll
        for (int nt = 0; nt < 4; ++nt) {
            atomicAdd(&sp[nt * 16 + l], sum[nt]);
            atomicAdd(&sp[64 + nt * 16 + l], sq[nt]);
        }
    }
#pragma unroll
    for (int g2 = 0; g2 < 2; ++g2)
#pragma unroll
        for (int j = 0; j < 8; ++j) {
            float v = pm[g2][j];
            v = fmaxf(v, __shfl_xor(v, 1, 64));
            v = fmaxf(v, __shfl_xor(v, 2, 64));
            v = fmaxf(v, __shfl_xor(v, 4, 64));
            v = fmaxf(v, __shfl_xor(v, 8, 64));
            pm[g2][j] = v;
        }
    if (r16 == 0) {
#pragma unroll
        for (int g2 = 0; g2 < 2; ++g2)
#pragma unroll
            for (int j = 0; j < 8; ++j)
                pooled[(size_t)bn * Uu + g2 * 32 + q * 8 + j] = pm[g2][j];
    }
}

// apply BN(i)+residual -> wnew (tile store). Wave-per-bn; x4 loads hoisted
// above MFMA in the guard-free main loop; mt=12 peeled. (R5 form, unchanged.)
template <bool FIRST>
__global__ __launch_bounds__(256, 3) void k_apply(
    const float* __restrict__ adj, f16* __restrict__ w16,
    const float* __restrict__ ew1, const float* __restrict__ eb1,
    const float* __restrict__ e0w, const float* __restrict__ e0b,
    const float* __restrict__ x3a, const float* __restrict__ x4a,
    const float* __restrict__ wss) {
    __shared__ __align__(16) f16 Et1[Uu * ETS];
    __shared__ __align__(16) float zbuf[4][16 * ZSH];
    int tid = threadIdx.x;
    stageEt(ew1, Et1, tid);
    int l = tid & 63, wv = tid >> 6;
    int r16 = l & 15, q = l >> 4;
    int bn = blockIdx.x * 4 + wv;
    int b = bn / Nn, n = bn % Nn;
    __syncthreads();

    // wn = wold + lrelu((zA + x4)*sc + (c1*sc + sh)), c1 = eb1 + x3a
    float scr[2][8], csr[2][8];
#pragma unroll
    for (int g2 = 0; g2 < 2; ++g2) {
        int ch = g2 * 32 + q * 8;
        float shv[8], c1v[8], ebv[8];
        *(float4*)&scr[g2][0] = *(const float4*)&wss[ch];
        *(float4*)&scr[g2][4] = *(const float4*)&wss[ch + 4];
        *(float4*)&shv[0] = *(const float4*)&wss[64 + ch];
        *(float4*)&shv[4] = *(const float4*)&wss[64 + ch + 4];
        *(float4*)&ebv[0] = *(const float4*)&eb1[ch];
        *(float4*)&ebv[4] = *(const float4*)&eb1[ch + 4];
        *(float4*)&c1v[0] = *(const float4*)&x3a[(size_t)bn * Uu + ch];
        *(float4*)&c1v[4] = *(const float4*)&x3a[(size_t)bn * Uu + ch + 4];
#pragma unroll
        for (int j = 0; j < 8; ++j)
            csr[g2][j] = fmaf(c1v[j] + ebv[j], scr[g2][j], shv[j]);
    }
    float e0r[2][8], e0br[2][8];
    if (FIRST) {
#pragma unroll
        for (int g2 = 0; g2 < 2; ++g2) {
            int ch = g2 * 32 + q * 8;
            *(float4*)&e0r[g2][0] = *(const float4*)&e0w[ch];
            *(float4*)&e0r[g2][4] = *(const float4*)&e0w[ch + 4];
            *(float4*)&e0br[g2][0] = *(const float4*)&e0b[ch];
            *(float4*)&e0br[g2][4] = *(const float4*)&e0b[ch + 4];
        }
    }

    const float* adjrow = adj + (size_t)bn * Nn;
    float* zb = zbuf[wv];

    float advc = 0.f;
    f16x8 A0c = (f16x8){0, 0, 0, 0, 0, 0, 0, 0}, A1c = A0c;
    if (FIRST) {
        advc = adjrow[dstcol(n, r16)];
    } else {
        size_t tb = tbase(bn, 0);
        A0c = ld8(w16 + tb + (size_t)l * 8);
        A1c = ld8(w16 + tb + 512 + (size_t)l * 8);
    }

    for (int mt = 0; mt < 12; ++mt) {  // guard-free rows
        int row = mt * 16 + r16;
        int dst = dstcol(n, row);
        size_t tb = tbase(bn, mt);
        float advn = 0.f;
        f16x8 A0n = (f16x8){0, 0, 0, 0, 0, 0, 0, 0}, A1n = A0n;
        if (FIRST) {
            int rn = row + 16;
            if (rn < NM1) advn = adjrow[dstcol(n, rn)];
        } else {
            size_t tbn = tbase(bn, mt + 1);
            A0n = ld8(w16 + tbn + (size_t)l * 8);
            A1n = ld8(w16 + tbn + 512 + (size_t)l * 8);
        }
        // hoisted x4 row loads (independent of MFMA)
        float x4v[2][8];
        {
            const float* x4r = x4a + (size_t)(b * Nn + dst) * Uu;
            *(float4*)&x4v[0][0] = *(const float4*)(x4r + q * 8);
            *(float4*)&x4v[0][4] = *(const float4*)(x4r + q * 8 + 4);
            *(float4*)&x4v[1][0] = *(const float4*)(x4r + 32 + q * 8);
            *(float4*)&x4v[1][4] = *(const float4*)(x4r + 32 + q * 8 + 4);
        }
        f16x8 A0, A1;
        float wold[2][8];
        if (FIRST) {
            float adv = advc;
#pragma unroll
            for (int j = 0; j < 8; ++j) {
                wold[0][j] = lrelu(fmaf(adv, e0r[0][j], e0br[0][j]));
                wold[1][j] = lrelu(fmaf(adv, e0r[1][j], e0br[1][j]));
                A0[j] = (f16)wold[0][j];
                A1[j] = (f16)wold[1][j];
            }
        } else {
            A0 = A0c;
            A1 = A1c;
#pragma unroll
            for (int j = 0; j < 8; ++j) {
                wold[0][j] = (float)A0[j];
                wold[1][j] = (float)A1[j];
            }
        }
        floatx4 acc[4];
#pragma unroll
        for (int nt = 0; nt < 4; ++nt) {
            f16x8 B0 = *(const f16x8*)&Et1[(nt * 16 + r16) * ETS + q * 8];
            f16x8 B1 = *(const f16x8*)&Et1[(nt * 16 + r16) * ETS + 32 + q * 8];
            acc[nt] = (floatx4){0, 0, 0, 0};
            acc[nt] = __builtin_amdgcn_mfma_f32_16x16x32_f16(A0, B0, acc[nt], 0, 0, 0);
            acc[nt] = __builtin_amdgcn_mfma_f32_16x16x32_f16(A1, B1, acc[nt], 0, 0, 0);
        }
        // C -> A transform, 2 phases (wave-private zbuf, in-order DS)
        float zA[2][8];
#pragma unroll
        for (int rr = 0; rr < 4; ++rr) {
            int zr = q * 4 + rr;
            zb[zr * ZSH + r16] = acc[0][rr];
            zb[zr * ZSH + 16 + r16] = acc[1][rr];
        }
        *(float4*)&zA[0][0] = *(const float4*)&zb[r16 * ZSH + q * 8];
        *(float4*)&zA[0][4] = *(const float4*)&zb[r16 * ZSH + q * 8 + 4];
#pragma unroll
        for (int rr = 0; rr < 4; ++rr) {
            int zr = q * 4 + rr;
            zb[zr * ZSH + r16] = acc[2][rr];
            zb[zr * ZSH + 16 + r16] = acc[3][rr];
        }
        *(float4*)&zA[1][0] = *(const float4*)&zb[r16 * ZSH + q * 8];
        *(float4*)&zA[1][4] = *(const float4*)&zb[r16 * ZSH + q * 8 + 4];

        f16x8 W0, W1;
#pragma unroll
        for (int g2 = 0; g2 < 2; ++g2) {
#pragma unroll
            for (int j = 0; j < 8; ++j) {
                float z = zA[g2][j] + x4v[g2][j];
                float wn = wold[g2][j] + lrelu(fmaf(z, scr[g2][j], csr[g2][j]));
                if (g2 == 0) W0[j] = (f16)wn;
                else W1[j] = (f16)wn;
            }
        }
        st8(w16 + tb + (size_t)l * 8, W0);
        st8(w16 + tb + 512 + (size_t)l * 8, W1);
        advc = advn;
        A0c = A0n;
        A1c = A1n;
    }
    {  // mt = 12 tail, guarded
        const int mt = 12;
        int row = mt * 16 + r16;
        bool rv = row < NM1;
        int dst = dstcol(n, rv ? row : 0);
        size_t tb = tbase(bn, mt);
        f16x8 A0, A1;
        float wold[2][8];
        if (FIRST) {
            float adv = advc;
#pragma unroll
            for (int j = 0; j < 8; ++j) {
                wold[0][j] = lrelu(fmaf(adv, e0r[0][j], e0br[0][j]));
                wold[1][j] = lrelu(fmaf(adv, e0r[1][j], e0br[1][j]));
                A0[j] = (f16)wold[0][j];
                A1[j] = (f16)wold[1][j];
            }
        } else {
            A0 = A0c;
            A1 = A1c;
#pragma unroll
            for (int j = 0; j < 8; ++j) {
                wold[0][j] = (float)A0[j];
                wold[1][j] = (float)A1[j];
            }
        }
        floatx4 acc[4];
#pragma unroll
        for (int nt = 0; nt < 4; ++nt) {
            f16x8 B0 = *(const f16x8*)&Et1[(nt * 16 + r16) * ETS + q * 8];
            f16x8 B1 = *(const f16x8*)&Et1[(nt * 16 + r16) * ETS + 32 + q * 8];
            acc[nt] = (floatx4){0, 0, 0, 0};
            acc[nt] = __builtin_amdgcn_mfma_f32_16x16x32_f16(A0, B0, acc[nt], 0, 0, 0);
            acc[nt] = __builtin_amdgcn_mfma_f32_16x16x32_f16(A1, B1, acc[nt], 0, 0, 0);
        }
        float zA[2][8];
#pragma unroll
        for (int rr = 0; rr < 4; ++rr) {
            int zr = q * 4 + rr;
            zb[zr * ZSH + r16] = acc[0][rr];
            zb[zr * ZSH + 16 + r16] = acc[1][rr];
        }
        *(float4*)&zA[0][0] = *(const float4*)&zb[r16 * ZSH + q * 8];
        *(float4*)&zA[0][4] = *(const float4*)&zb[r16 * ZSH + q * 8 + 4];
#pragma unroll
        for (int rr = 0; rr < 4; ++rr) {
            int zr = q * 4 + rr;
            zb[zr * ZSH + r16] = acc[2][rr];
            zb[zr * ZSH + 16 + r16] = acc[3][rr];
        }
        *(float4*)&zA[1][0] = *(const float4*)&zb[r16 * ZSH + q * 8];
        *(float4*)&zA[1][4] = *(const float4*)&zb[r16 * ZSH + q * 8 + 4];

        float x4v[2][8] = {{0, 0, 0, 0, 0, 0, 0, 0}, {0, 0, 0, 0, 0, 0, 0, 0}};
        if (rv) {
            const float* x4r = x4a + (size_t)(b * Nn + dst) * Uu;
            *(float4*)&x4v[0][0] = *(const float4*)(x4r + q * 8);
            *(float4*)&x4v[0][4] = *(const float4*)(x4r + q * 8 + 4);
            *(float4*)&x4v[1][0] = *(const float4*)(x4r + 32 + q * 8);
            *(float4*)&x4v[1][4] = *(const float4*)(x4r + 32 + q * 8 + 4);
        }
        f16x8 W0, W1;
#pragma unroll
        for (int g2 = 0; g2 < 2; ++g2) {
#pragma unroll
            for (int j = 0; j < 8; ++j) {
                float z = zA[g2][j] + x4v[g2][j];
                float wn = wold[g2][j] + lrelu(fmaf(z, scr[g2][j], csr[g2][j]));
                if (g2 == 0) W0[j] = (f16)wn;
                else W1[j] = (f16)wn;
            }
        }
        st8(w16 + tb + (size_t)l * 8, W0);
        st8(w16 + tb + 512 + (size_t)l * 8, W1);
    }
}

// stats pass (+ optional pool of sig(w)*x2): 8 bn per block, 512 threads,
// x4[b] slab in LDS (same rationale as k_first).
template <bool POOL>
__global__ __launch_bounds__(512, 2) void k_p1s(
    const f16* __restrict__ w16, const float* __restrict__ ew2,
    const float* __restrict__ eb2, const float* __restrict__ x3b,
    const float* __restrict__ x4b, const float* __restrict__ x2b,
    float* __restrict__ spread, float* __restrict__ pooled) {
    __shared__ __align__(16) f16 Et[Uu * ETS];      // 9216 B
    __shared__ __align__(16) float x4L[Nn * Uu];    // 51200 B
    int tid = threadIdx.x;
    stageEt512(ew2, Et, tid);
    int l = tid & 63, wv = tid >> 6;
    int r16 = l & 15, q = l >> 4;
    int bn = blockIdx.x * 8 + wv;
    int b = (blockIdx.x * 8) / Nn;
    int n = bn % Nn;
    {
        const float4* src = (const float4*)(x4b + (size_t)b * Nn * Uu);
        float4* dstp = (float4*)x4L;
        for (int i = tid; i < (Nn * Uu) / 4; i += 512) dstp[i] = src[i];
    }
    __syncthreads();

    f16x8 B0r[4], B1r[4];
    float c2v[4];
#pragma unroll
    for (int nt = 0; nt < 4; ++nt) {
        B0r[nt] = *(const f16x8*)&Et[(nt * 16 + r16) * ETS + q * 8];
        B1r[nt] = *(const f16x8*)&Et[(nt * 16 + r16) * ETS + 32 + q * 8];
        int u = nt * 16 + r16;
        c2v[nt] = eb2[u] + x3b[(size_t)bn * Uu + u];
    }

    float sum[4] = {0, 0, 0, 0}, sq[4] = {0, 0, 0, 0};
    float pm[2][8];
    if (POOL) {
#pragma unroll
        for (int g2 = 0; g2 < 2; ++g2)
#pragma unroll
            for (int j = 0; j < 8; ++j) pm[g2][j] = -3.402823e38f;
    }

    f16x8 A0c, A1c;
    {
        size_t tb = tbase(bn, 0);
        A0c = ld8(w16 + tb + (size_t)l * 8);
        A1c = ld8(w16 + tb + 512 + (size_t)l * 8);
    }

    for (int mt = 0; mt < 12; ++mt) {  // guard-free
        int row = mt * 16 + r16;
        int dst = dstcol(n, row);
        f16x8 A0n, A1n;
        {
            size_t tbn = tbase(bn, mt + 1);
            A0n = ld8(w16 + tbn + (size_t)l * 8);
            A1n = ld8(w16 + tbn + 512 + (size_t)l * 8);
        }
        // stats gather from LDS slab
        float xs[4][4];
#pragma unroll
        for (int rr = 0; rr < 4; ++rr) {
            const float* x4r = x4L + dstcol(n, mt * 16 + q * 4 + rr) * Uu;
#pragma unroll
            for (int nt = 0; nt < 4; ++nt) xs[rr][nt] = x4r[nt * 16 + r16];
        }
        float xv[2][8];
        if (POOL) {
            const float* x2r = x2b + (size_t)(b * Nn + dst) * Uu;
            *(float4*)&xv[0][0] = *(const float4*)(x2r + q * 8);
            *(float4*)&xv[0][4] = *(const float4*)(x2r + q * 8 + 4);
            *(float4*)&xv[1][0] = *(const float4*)(x2r + 32 + q * 8);
            *(float4*)&xv[1][4] = *(const float4*)(x2r + 32 + q * 8 + 4);
        }
        f16x8 A0 = A0c, A1 = A1c;
        floatx4 acc[4];
#pragma unroll
        for (int nt = 0; nt < 4; ++nt) {
            acc[nt] = (floatx4){0, 0, 0, 0};
            acc[nt] = __builtin_amdgcn_mfma_f32_16x16x32_f16(A0, B0r[nt], acc[nt], 0, 0, 0);
            acc[nt] = __builtin_amdgcn_mfma_f32_16x16x32_f16(A1, B1r[nt], acc[nt], 0, 0, 0);
        }
#pragma unroll
        for (int rr = 0; rr < 4; ++rr)
#pragma unroll
            for (int nt = 0; nt < 4; ++nt) {
                float z = acc[nt][rr] + c2v[nt] + xs[rr][nt];
                sum[nt] += z;
                sq[nt] = fmaf(z, z, sq[nt]);
            }
        if (POOL) {
#pragma unroll
            for (int g2 = 0; g2 < 2; ++g2)
#pragma unroll
                for (int j = 0; j < 8; ++j) {
                    float wv_ = (float)(g2 == 0 ? A0[j] : A1[j]);
                    pm[g2][j] = fmaxf(pm[g2][j], sigm(wv_) * xv[g2][j]);
                }
        }
        A0c = A0n;
        A1c = A1n;
    }
    {  // mt = 12 tail, guarded
        const int mt = 12;
        int row = mt * 16 + r16;
        bool rv = row < NM1;
        f16x8 A0 = A0c, A1 = A1c;
        floatx4 acc[4];
#pragma unroll
        for (int nt = 0; nt < 4; ++nt) {
            acc[nt] = (floatx4){0, 0, 0, 0};
            acc[nt] = __builtin_amdgcn_mfma_f32_16x16x32_f16(A0, B0r[nt], acc[nt], 0, 0, 0);
            acc[nt] = __builtin_amdgcn_mfma_f32_16x16x32_f16(A1, B1r[nt], acc[nt], 0, 0, 0);
        }
#pragma unroll
        for (int rr = 0; rr < 4; ++rr) {
            int k = mt * 16 + q * 4 + rr;
            if (k < NM1) {
                const float* x4r = x4L + dstcol(n, k) * Uu;
#pragma unroll
                for (int nt = 0; nt < 4; ++nt) {
                    float z = acc[nt][rr] + c2v[nt] + x4r[nt * 16 + r16];
                    sum[nt] += z;
                    sq[nt] = fmaf(z, z, sq[nt]);
                }
            }
        }
        if (POOL && rv) {
            int dst = dstcol(n, row);
            const float* x2r = x2b + (size_t)(b * Nn + dst) * Uu;
#pragma unroll
            for (int g2 = 0; g2 < 2; ++g2) {
                float xv[8];
                *(float4*)&xv[0] = *(const float4*)(x2r + g2 * 32 + q * 8);
                *(float4*)&xv[4] = *(const float4*)(x2r + g2 * 32 + q * 8 + 4);
#pragma unroll
                for (int j = 0; j < 8; ++j) {
                    float wv_ = (float)(g2 == 0 ? A0[j] : A1[j]);
                    pm[g2][j] = fmaxf(pm[g2][j], sigm(wv_) * xv[j]);
                }
            }
        }
    }
#pragma unroll
    for (int nt = 0; nt < 4; ++nt) {
        sum[nt] += __shfl_xor(sum[nt], 16, 64);
        sum[nt] += __shfl_xor(sum[nt], 32, 64);
        sq[nt] += __shfl_xor(sq[nt], 16, 64);
        sq[nt] += __shfl_xor(sq[nt], 32, 64);
    }
    float* sp = spread + (size_t)(bn & (SPREAD - 1)) * 128;
    if (l < 16) {
#pragma unroll
        for (int nt = 0; nt < 4; ++nt) {
            atomicAdd(&sp[nt * 16 + l], sum[nt]);
            atomicAdd(&sp[64 + nt * 16 + l], sq[nt]);
        }
    }
    if (POOL) {
#pragma unroll
        for (int g2 = 0; g2 < 2; ++g2)
#pragma unroll
            for (int j = 0; j < 8; ++j) {
                float v = pm[g2][j];
                v = fmaxf(v, __shfl_xor(v, 1, 64));
                v = fmaxf(v, __shfl_xor(v, 2, 64));
                v = fmaxf(v, __shfl_xor(v, 4, 64));
                v = fmaxf(v, __shfl_xor(v, 8, 64));
                pm[g2][j] = v;
            }
        if (r16 == 0) {
#pragma unroll
            for (int g2 = 0; g2 < 2; ++g2)
#pragma unroll
                for (int j = 0; j < 8; ++j)
                    pooled[(size_t)bn * Uu + g2 * 32 + q * 8 + j] = pm[g2][j];
        }
    }
}

// last: apply BN(2)+residual, dot with e_lin1, scatter to out; wave-per-bn
__global__ __launch_bounds__(256, 3) void k_last(
    const f16* __restrict__ w16, const float* __restrict__ ew1,
    const float* __restrict__ eb1, const float* __restrict__ x3a,
    const float* __restrict__ x4a, const float* __restrict__ wss,
    const float* __restrict__ elw, const float* __restrict__ elb,
    float* __restrict__ out) {
    __shared__ __align__(16) f16 Et1[Uu * ETS];
    __shared__ __align__(16) float zbuf[4][16 * ZSH];
    int tid = threadIdx.x;
    stageEt(ew1, Et1, tid);
    int l = tid & 63, wv = tid >> 6;
    int r16 = l & 15, q = l >> 4;
    int bn = blockIdx.x * 4 + wv;
    int b = bn / Nn, n = bn % Nn;
    __syncthreads();

    float scr[2][8], csr[2][8], elr[2][8];
#pragma unroll
    for (int g2 = 0; g2 < 2; ++g2) {
        int ch = g2 * 32 + q * 8;
        float shv[8], c1v[8], ebv[8];
        *(float4*)&scr[g2][0] = *(const float4*)&wss[ch];
        *(float4*)&scr[g2][4] = *(const float4*)&wss[ch + 4];
        *(float4*)&shv[0] = *(const float4*)&wss[64 + ch];
        *(float4*)&shv[4] = *(const float4*)&wss[64 + ch + 4];
        *(float4*)&ebv[0] = *(const float4*)&eb1[ch];
        *(float4*)&ebv[4] = *(const float4*)&eb1[ch + 4];
        *(float4*)&c1v[0] = *(const float4*)&x3a[(size_t)bn * Uu + ch];
        *(float4*)&c1v[4] = *(const float4*)&x3a[(size_t)bn * Uu + ch + 4];
        *(float4*)&elr[g2][0] = *(const float4*)&elw[ch];
        *(float4*)&elr[g2][4] = *(const float4*)&elw[ch + 4];
#pragma unroll
        for (int j = 0; j < 8; ++j)
            csr[g2][j] = fmaf(c1v[j] + ebv[j], scr[g2][j], shv[j]);
    }

    float elb0 = elb[0];
    float* zb = zbuf[wv];

    f16x8 A0c, A1c;
    {
        size_t tb = tbase(bn, 0);
        A0c = ld8(w16 + tb + (size_t)l * 8);
        A1c = ld8(w16 + tb + 512 + (size_t)l * 8);
    }

    for (int mt = 0; mt < 12; ++mt) {  // guard-free
        int row = mt * 16 + r16;
        int dst = dstcol(n, row);
        f16x8 A0n, A1n;
        {
            size_t tbn = tbase(bn, mt + 1);
            A0n = ld8(w16 + tbn + (size_t)l * 8);
            A1n = ld8(w16 + tbn + 512 + (size_t)l * 8);
        }
        // hoisted x4 loads
        float x4v[2][8];
        {
            const float* x4r = x4a + (size_t)(b * Nn + dst) * Uu;
            *(float4*)&x4v[0][0] = *(const float4*)(x4r + q * 8);
            *(float4*)&x4v[0][4] = *(const float4*)(x4r + q * 8 + 4);
            *(float4*)&x4v[1][0] = *(const float4*)(x4r + 32 + q * 8);
            *(float4*)&x4v[1][4] = *(const float4*)(x4r + 32 + q * 8 + 4);
        }
        f16x8 A0 = A0c, A1 = A1c;
        float wold[2][8];
#pragma unroll
        for (int j = 0; j < 8; ++j) {
            wold[0][j] = (float)A0[j];
            wold[1][j] = (float)A1[j];
        }
        floatx4 acc[4];
#pragma unroll
        for (int nt = 0; nt < 4; ++nt) {
            f16x8 B0 = *(const f16x8*)&Et1[(nt * 16 + r16) * ETS + q * 8];
            f16x8 B1 = *(const f16x8*)&Et1[(nt * 16 + r16) * ETS + 32 + q * 8];
            acc[nt] = (floatx4){0, 0, 0, 0};
            acc[nt] = __builtin_amdgcn_mfma_f32_16x16x32_f16(A0, B0, acc[nt], 0, 0, 0);
            acc[nt] = __builtin_amdgcn_mfma_f32_16x16x32_f16(A1, B1, acc[nt], 0, 0, 0);
        }
        float zA[2][8];
#pragma unroll
        for (int rr = 0; rr < 4; ++rr) {
            int zr = q * 4 + rr;
            zb[zr * ZSH + r16] = acc[0][rr];
            zb[zr * ZSH + 16 + r16] = acc[1][rr];
        }
        *(float4*)&zA[0][0] = *(const float4*)&zb[r16 * ZSH + q * 8];
        *(float4*)&zA[0][4] = *(const float4*)&zb[r16 * ZSH + q * 8 + 4];
#pragma unroll
        for (int rr = 0; rr < 4; ++rr) {
            int zr = q * 4 + rr;
            zb[zr * ZSH + r16] = acc[2][rr];
            zb[zr * ZSH + 16 + r16] = acc[3][rr];
        }
        *(float4*)&zA[1][0] = *(const float4*)&zb[r16 * ZSH + q * 8];
        *(float4*)&zA[1][4] = *(const float4*)&zb[r16 * ZSH + q * 8 + 4];

        float t = 0.f;
#pragma unroll
        for (int g2 = 0; g2 < 2; ++g2) {
#pragma unroll
            for (int j = 0; j < 8; ++j) {
                float z = zA[g2][j] + x4v[g2][j];
                float wn = wold[g2][j] + lrelu(fmaf(z, scr[g2][j], csr[g2][j]));
                t = fmaf(wn, elr[g2][j], t);
            }
        }
        t += __shfl_xor(t, 16, 64);
        t += __shfl_xor(t, 32, 64);
        if (q == 0) out[(size_t)bn * Nn + dst] = t + elb0;
        A0c = A0n;
        A1c = A1n;
    }
    {  // mt = 12 tail, guarded
        const int mt = 12;
        int row = mt * 16 + r16;
        bool rv = row < NM1;
        int dst = dstcol(n, rv ? row : 0);
        f16x8 A0 = A0c, A1 = A1c;
        float wold[2][8];
#pragma unroll
        for (int j = 0; j < 8; ++j) {
            wold[0][j] = (float)A0[j];
            wold[1][j] = (float)A1[j];
        }
        floatx4 acc[4];
#pragma unroll
        for (int nt = 0; nt < 4; ++nt) {
            f16x8 B0 = *(const f16x8*)&Et1[(nt * 16 + r16) * ETS + q * 8];
            f16x8 B1 = *(const f16x8*)&Et1[(nt * 16 + r16) * ETS + 32 + q * 8];
            acc[nt] = (floatx4){0, 0, 0, 0};
            acc[nt] = __builtin_amdgcn_mfma_f32_16x16x32_f16(A0, B0, acc[nt], 0, 0, 0);
            acc[nt] = __builtin_amdgcn_mfma_f32_16x16x32_f16(A1, B1, acc[nt], 0, 0, 0);
        }
        float zA[2][8];
#pragma unroll
        for (int rr = 0; rr < 4; ++rr) {
            int zr = q * 4 + rr;
            zb[zr * ZSH + r16] = acc[0][rr];
            zb[zr * ZSH + 16 + r16] = acc[1][rr];
        }
        *(float4*)&zA[0][0] = *(const float4*)&zb[r16 * ZSH + q * 8];
        *(float4*)&zA[0][4] = *(const float4*)&zb[r16 * ZSH + q * 8 + 4];
#pragma unroll
        for (int rr = 0; rr < 4; ++rr) {
            int zr = q * 4 + rr;
            zb[zr * ZSH + r16] = acc[2][rr];
            zb[zr * ZSH + 16 + r16] = acc[3][rr];
        }
        *(float4*)&zA[1][0] = *(const float4*)&zb[r16 * ZSH + q * 8];
        *(float4*)&zA[1][4] = *(const float4*)&zb[r16 * ZSH + q * 8 + 4];

        float x4v[2][8] = {{0, 0, 0, 0, 0, 0, 0, 0}, {0, 0, 0, 0, 0, 0, 0, 0}};
        if (rv) {
            const float* x4r = x4a + (size_t)(b * Nn + dst) * Uu;
            *(float4*)&x4v[0][0] = *(const float4*)(x4r + q * 8);
            *(float4*)&x4v[0][4] = *(const float4*)(x4r + q * 8 + 4);
            *(float4*)&x4v[1][0] = *(const float4*)(x4r + 32 + q * 8);
            *(float4*)&x4v[1][4] = *(const float4*)(x4r + 32 + q * 8 + 4);
        }
        float t = 0.f;
#pragma unroll
        for (int g2 = 0; g2 < 2; ++g2) {
#pragma unroll
            for (int j = 0; j < 8; ++j) {
                float z = zA[g2][j] + x4v[g2][j];
                float wn = wold[g2][j] + lrelu(fmaf(z, scr[g2][j], csr[g2][j]));
                t = fmaf(wn, elr[g2][j], t);
            }
        }
        t += __shfl_xor(t, 16, 64);
        t += __shfl_xor(t, 32, 64);
        if (q == 0 && rv) out[(size_t)bn * Nn + dst] = t + elb0;
    }
    if (l == 0) out[(size_t)bn * Nn + n] = 0.f;
}

// finw (block 64) + hup (blocks 0..63)
__global__ void k_mid(const float* __restrict__ spread, const float* __restrict__ eg,
                      const float* __restrict__ ebb, float* __restrict__ wss,
                      const float* __restrict__ x1, const float* __restrict__ pooled,
                      const float* __restrict__ vg, const float* __restrict__ vbb,
                      float* __restrict__ h) {
    if (blockIdx.x == 64) {
        int u = threadIdx.x;
        if (u < 64) {
            float s = 0.f, sqv = 0.f;
            for (int p = 0; p < SPREAD; ++p) {
                s += spread[p * 128 + u];
                sqv += spread[p * 128 + 64 + u];
            }
            const float Mf = (float)((size_t)Bb * Nn * NM1);
            float mean = s / Mf;
            float var = fmaxf(sqv / Mf - mean * mean, 0.f);
            float inv = rsqrtf(var + EPSBN);
            float scale = eg[u] * inv;
            wss[u] = scale;
            wss[64 + u] = ebb[u] - mean * scale;
        }
        return;
    }
    __shared__ float red[256], red2[256];
    int ch = blockIdx.x;
    int t = threadIdx.x;
    float s = 0.f, sqv = 0.f;
    for (int bn = t; bn < Bb * Nn; bn += 256) {
        float v = x1[bn * Uu + ch] + pooled[bn * Uu + ch];
        s += v;
        sqv = fmaf(v, v, sqv);
    }
    red[t] = s;
    red2[t] = sqv;
    __syncthreads();
    for (int off = 128; off; off >>= 1) {
        if (t < off) {
            red[t] += red[t + off];
            red2[t] += red2[t + off];
        }
        __syncthreads();
    }
    const float Mf = (float)(Bb * Nn);
    float mean = red[0] / Mf;
    float var = fmaxf(red2[0] / Mf - mean * mean, 0.f);
    float inv = rsqrtf(var + EPSBN);
    float scale = vg[ch] * inv;
    float shift = vbb[ch] - mean * scale;
    for (int bn = t; bn < Bb * Nn; bn += 256) {
        float v = x1[bn * Uu + ch] + pooled[bn * Uu + ch];
        h[bn * Uu + ch] += lrelu(fmaf(v, scale, shift));
    }
}

__global__ void k_finw(const float* __restrict__ spread, const float* __restrict__ g,
                       const float* __restrict__ bb, float* __restrict__ wss) {
    int u = threadIdx.x;
    float s = 0.f, sq = 0.f;
    for (int p = 0; p < SPREAD; ++p) {
        s += spread[p * 128 + u];
        sq += spread[p * 128 + 64 + u];
    }
    const float Mf = (float)((size_t)Bb * Nn * NM1);
    float mean = s / Mf;
    float var = fmaxf(sq / Mf - mean * mean, 0.f);
    float inv = rsqrtf(var + EPSBN);
    float scale = g[u] * inv;
    wss[u] = scale;
    wss[64 + u] = bb[u] - mean * scale;
}

extern "C" void kernel_launch(void* const* d_in, const int* in_sizes, int n_in,
                              void* d_out, int out_size, void* d_ws, size_t ws_size,
                              hipStream_t stream) {
    const float* x = (const float*)d_in[0];
    const float* adj = (const float*)d_in[1];
    const float* vl0w = (const float*)d_in[2];
    const float* vl0b = (const float*)d_in[3];
    const float* vw1 = (const float*)d_in[4];
    const float* vb1 = (const float*)d_in[5];
    const float* vw2 = (const float*)d_in[6];
    const float* vb2 = (const float*)d_in[7];
    const float* vw3 = (const float*)d_in[8];
    const float* vb3 = (const float*)d_in[9];
    const float* vw4 = (const float*)d_in[10];
    const float* vb4 = (const float*)d_in[11];
    const float* vbng = (const float*)d_in[12];
    const float* vbnb = (const float*)d_in[13];
    const float* e0w = (const float*)d_in[14];
    const float* e0b = (const float*)d_in[15];
    const float* ew = (const float*)d_in[16];
    const float* eb = (const float*)d_in[17];
    const float* ebng = (const float*)d_in[18];
    const float* ebnb = (const float*)d_in[19];
    const float* elw = (const float*)d_in[20];
    const float* elb = (const float*)d_in[21];
    float* out = (float*)d_out;

    f16* w16 = (f16*)d_ws;                      // 3200*13*1024 = 42,598,400 f16
    float* fb = (float*)d_ws + 21299200;
    const size_t NV = 204800;
    float* h = fb;
    float* xv1[3] = {fb + NV, fb + 2 * NV, fb + 3 * NV};
    float* xv2[3] = {fb + 4 * NV, fb + 5 * NV, fb + 6 * NV};
    float* xv3[3] = {fb + 7 * NV, fb + 8 * NV, fb + 9 * NV};
    float* xv4[3] = {fb + 10 * NV, fb + 11 * NV, fb + 12 * NV};
    float* pooled = fb + 13 * NV;
    float* spread = fb + 14 * NV;               // SPREAD*128
    float* wss = spread + SPREAD * 128;         // 128

    const int GRID4 = (Bb * Nn) / 4;  // 800 blocks: xvec/apply/last
    const int GRID8 = (Bb * Nn) / 8;  // 400 blocks: first/p1s (512 thr, slab)

    // layer 0
    k_xvec<true><<<GRID4, 256, 0, stream>>>(x, vl0w, vl0b, h, vw1, vb1, vw2, vb2,
                                            vw3, vb3, vw4, vb4, xv1[0], xv2[0],
                                            xv3[0], xv4[0], spread);
    k_first<<<GRID8, 512, 0, stream>>>(adj, ew, eb, e0w, e0b, xv2[0], xv3[0], xv4[0],
                                       pooled, spread);
    k_mid<<<65, 256, 0, stream>>>(spread, ebng, ebnb, wss, xv1[0], pooled, vbng,
                                  vbnb, h);
    // layer 1
    k_xvec<false><<<GRID4, 256, 0, stream>>>(x, vl0w, vl0b, h, vw1 + 4096, vb1 + 64,
                                             vw2 + 4096, vb2 + 64, vw3 + 4096,
                                             vb3 + 64, vw4 + 4096, vb4 + 64, xv1[1],
                                             xv2[1], xv3[1], xv4[1], spread);
    k_apply<true><<<GRID4, 256, 0, stream>>>(adj, w16, ew, eb, e0w, e0b, xv3[0],
                                             xv4[0], wss);
    k_p1s<true><<<GRID8, 512, 0, stream>>>(w16, ew + 4096, eb + 64, xv3[1], xv4[1],
                                           xv2[1], spread, pooled);
    k_mid<<<65, 256, 0, stream>>>(spread, ebng + 64, ebnb + 64, wss, xv1[1], pooled,
                                  vbng + 64, vbnb + 64, h);
    // layer 2 (h-path after layer 2 is dead: no pool, no h update)
    k_xvec<false><<<GRID4, 256, 0, stream>>>(x, vl0w, vl0b, h, vw1 + 8192, vb1 + 128,
                                             vw2 + 8192, vb2 + 128, vw3 + 8192,
                                             vb3 + 128, vw4 + 8192, vb4 + 128,
                                             xv1[2], xv2[2], xv3[2], xv4[2], spread);
    k_apply<false><<<GRID4, 256, 0, stream>>>(adj, w16, ew + 4096, eb + 64, e0w, e0b,
                                              xv3[1], xv4[1], wss);
    k_p1s<false><<<GRID8, 512, 0, stream>>>(w16, ew + 8192, eb + 128, xv3[2], xv4[2],
                                            xv2[2], spread, pooled);
    k_finw<<<1, 64, 0, stream>>>(spread, ebng + 128, ebnb + 128, wss);
    k_last<<<GRID4, 256, 0, stream>>>(w16, ew + 8192, eb + 128, xv3[2], xv4[2], wss,
                                      elw, elb, out);
}